// Round 1
// baseline (1350.884 us; speedup 1.0000x reference)
//
#include <hip/hip_runtime.h>
#include <math.h>

#define NB 16
#define NN 4096
#define DD 512
#define NSL 16
#define HH 512
#define NITERS 3
#define MROWS 256          // B*NS
#define SCALE_F 0.044194173824159216f
#define LN_EPS_F 1e-5f
#define ATTN_EPS_F 1e-8f

typedef float4 f4;

__device__ __forceinline__ float dot4f(f4 a, f4 b){
    return a.x*b.x + a.y*b.y + a.z*b.z + a.w*b.w;
}

// ---------------- broadcast slots_mu -> slots (B,NS,D) ----------------
__global__ __launch_bounds__(256) void k_bcast(const float* __restrict__ mu, float* __restrict__ slots){
    int idx = blockIdx.x*256 + threadIdx.x;           // over 32768 float4
    const f4* mu4 = (const f4*)mu;                    // 2048 float4
    f4* s4 = (f4*)slots;
    s4[idx] = mu4[idx & 2047];
}

// ---------------- per-row mean/rstd of v_inp ----------------
__global__ __launch_bounds__(256) void k_vstats(const float* __restrict__ v, float* __restrict__ vmu, float* __restrict__ vrstd){
    int row = blockIdx.x*256 + threadIdx.x;           // 65536 rows
    const f4* r4 = (const f4*)(v + (size_t)row*DD);
    float s = 0.f, ss = 0.f;
    for (int c = 0; c < DD/4; c++){
        f4 x = r4[c];
        s  += x.x + x.y + x.z + x.w;
        ss += x.x*x.x + x.y*x.y + x.z*x.z + x.w*x.w;
    }
    float m = s * (1.0f/DD);
    float var = ss * (1.0f/DD) - m*m;
    vmu[row] = m;
    vrstd[row] = rsqrtf(var + LN_EPS_F);
}

// ---------------- LayerNorm over 256 rows of 512 ----------------
__global__ __launch_bounds__(64) void k_ln_rows(const float* __restrict__ x, const float* __restrict__ g,
                                                const float* __restrict__ bb, float* __restrict__ y){
    int row = blockIdx.x;
    int t = threadIdx.x;                               // 64 threads = 1 wave
    const f4* r4 = (const f4*)(x + (size_t)row*DD);
    f4 v0 = r4[t*2], v1 = r4[t*2+1];
    float s  = v0.x+v0.y+v0.z+v0.w + v1.x+v1.y+v1.z+v1.w;
    float ss = v0.x*v0.x+v0.y*v0.y+v0.z*v0.z+v0.w*v0.w
             + v1.x*v1.x+v1.y*v1.y+v1.z*v1.z+v1.w*v1.w;
    for (int o = 32; o; o >>= 1){ s += __shfl_down(s,o); ss += __shfl_down(ss,o); }
    s = __shfl(s, 0); ss = __shfl(ss, 0);
    float mu = s * (1.0f/DD);
    float rstd = rsqrtf(ss * (1.0f/DD) - mu*mu + LN_EPS_F);
    const f4* g4 = (const f4*)g; const f4* b4 = (const f4*)bb;
    f4* y4 = (f4*)(y + (size_t)row*DD);
    f4 g0 = g4[t*2], g1 = g4[t*2+1], c0 = b4[t*2], c1 = b4[t*2+1];
    f4 o0, o1;
    o0.x = (v0.x-mu)*rstd*g0.x + c0.x; o0.y = (v0.y-mu)*rstd*g0.y + c0.y;
    o0.z = (v0.z-mu)*rstd*g0.z + c0.z; o0.w = (v0.w-mu)*rstd*g0.w + c0.w;
    o1.x = (v1.x-mu)*rstd*g1.x + c1.x; o1.y = (v1.y-mu)*rstd*g1.y + c1.y;
    o1.z = (v1.z-mu)*rstd*g1.z + c1.z; o1.w = (v1.w-mu)*rstd*g1.w + c1.w;
    y4[t*2] = o0; y4[t*2+1] = o1;
}

// ---------------- q = s@Wq^T + bq ; qg = q*gk ; C1=sum(qg) ; C2=sum(q*bk) ----------------
// grid (8 c-chunks, 16 m-groups), block 256. lane=c, wave -> 4 m's.
__global__ __launch_bounds__(256) void k_q(const float* __restrict__ s, const float* __restrict__ Wq,
                                           const float* __restrict__ bq, const float* __restrict__ gk,
                                           const float* __restrict__ bk, float* __restrict__ qg,
                                           float* __restrict__ C1, float* __restrict__ C2){
    int lane = threadIdx.x & 63;
    int wv = threadIdx.x >> 6;
    int c = blockIdx.x*64 + lane;
    int m0 = blockIdx.y*16 + wv*4;
    const f4* w4 = (const f4*)(Wq + (size_t)c*DD);
    const f4* s4 = (const f4*)s;
    float acc[4] = {0.f,0.f,0.f,0.f};
    for (int k = 0; k < DD/4; k++){
        f4 w = w4[k];
#pragma unroll
        for (int mm = 0; mm < 4; mm++)
            acc[mm] += dot4f(s4[(size_t)(m0+mm)*(DD/4) + k], w);
    }
    float gkc = gk[c], bkc = bk[c], bqc = bq[c];
#pragma unroll
    for (int mm = 0; mm < 4; mm++){
        float qv = acc[mm] + bqc;
        float qgv = qv * gkc;
        qg[(size_t)(m0+mm)*DD + c] = qgv;
        float r1 = qgv, r2 = qv * bkc;
        for (int o = 32; o; o >>= 1){ r1 += __shfl_down(r1,o); r2 += __shfl_down(r2,o); }
        if (lane == 0){ atomicAdd(&C1[m0+mm], r1); atomicAdd(&C2[m0+mm], r2); }
    }
}

// ---------------- phase 1: dots + softmax(slots axis) + attn + w ----------------
// grid (16 j-chunks, 16 b), block 256; thread owns one j-row of k.
__global__ __launch_bounds__(256) void k_phase1(const float* __restrict__ kin, const float* __restrict__ qg,
        const float* __restrict__ C1, const float* __restrict__ C2, const float* __restrict__ vrstd,
        float* __restrict__ attn, float* __restrict__ w){
    __shared__ f4 qg4[NSL*DD/4];     // 32 KB
    __shared__ float c1s[NSL], c2s[NSL];
    int b = blockIdx.y;
    int t = threadIdx.x;
    const f4* qgg = (const f4*)(qg + (size_t)b*NSL*DD);
    for (int idx = t; idx < NSL*DD/4; idx += 256) qg4[idx] = qgg[idx];
    if (t < NSL){ c1s[t] = C1[b*NSL+t]; c2s[t] = C2[b*NSL+t]; }
    __syncthreads();
    int j = blockIdx.x*256 + t;
    const f4* kr = (const f4*)(kin + ((size_t)b*NN + j)*DD);
    float acc[NSL];
#pragma unroll
    for (int i = 0; i < NSL; i++) acc[i] = 0.f;
    float s = 0.f, ss = 0.f;
    for (int dd = 0; dd < DD/4; dd++){
        f4 kv = kr[dd];
        s  += kv.x + kv.y + kv.z + kv.w;
        ss += kv.x*kv.x + kv.y*kv.y + kv.z*kv.z + kv.w*kv.w;
#pragma unroll
        for (int i = 0; i < NSL; i++) acc[i] += dot4f(qg4[i*(DD/4)+dd], kv);
    }
    float mu = s * (1.0f/DD);
    float rstd = rsqrtf(ss * (1.0f/DD) - mu*mu + LN_EPS_F);
    float dots[NSL], mx = -1e30f;
#pragma unroll
    for (int i = 0; i < NSL; i++){
        dots[i] = SCALE_F * (rstd*(acc[i] - mu*c1s[i]) + c2s[i]);
        mx = fmaxf(mx, dots[i]);
    }
    float se = 0.f;
#pragma unroll
    for (int i = 0; i < NSL; i++){ dots[i] = __expf(dots[i] - mx); se += dots[i]; }
    float inv = 1.0f / se;
    float rv = vrstd[b*NN + j];
#pragma unroll
    for (int i = 0; i < NSL; i++){
        float a = dots[i]*inv + ATTN_EPS_F;
        attn[((size_t)b*NSL + i)*NN + j] = a;
        w[((size_t)b*NSL + i)*NN + j] = a * rv;
    }
}

// ---------------- S[b,i] = sum_j attn ; M[b,i] = sum_j w*mu_v ----------------
__global__ __launch_bounds__(256) void k_reduceSM(const float* __restrict__ attn, const float* __restrict__ w,
        const float* __restrict__ vmu, float* __restrict__ S, float* __restrict__ Mm){
    int i = blockIdx.x, b = blockIdx.y, t = threadIdx.x;
    const float* ar = attn + ((size_t)b*NSL + i)*NN;
    const float* wr = w + ((size_t)b*NSL + i)*NN;
    const float* mr = vmu + (size_t)b*NN;
    float s = 0.f, m = 0.f;
    for (int j = t; j < NN; j += 256){ s += ar[j]; m += wr[j]*mr[j]; }
    __shared__ float sh0[256], sh1[256];
    sh0[t] = s; sh1[t] = m; __syncthreads();
    for (int o = 128; o; o >>= 1){
        if (t < o){ sh0[t] += sh0[t+o]; sh1[t] += sh1[t+o]; }
        __syncthreads();
    }
    if (t == 0){ S[b*NSL+i] = sh0[0]; Mm[b*NSL+i] = sh1[0]; }
}

// ---------------- phase 2: Uw[i,d] += sum_j w_ij * v_raw[j,d] ----------------
// grid (16 j-chunks, 16 b), block 256; thread owns d-pair (2t,2t+1).
__global__ __launch_bounds__(256) void k_phase2(const float* __restrict__ vin, const float* __restrict__ w,
                                                float* __restrict__ Uw){
    int b = blockIdx.y;
    int jc = blockIdx.x*256;
    int t = threadIdx.x;
    __shared__ float wl[256*20];      // [jj][i] with stride 20 (16B-aligned rows, bank-spread)
    for (int idx = t; idx < NSL*256; idx += 256){
        int i = idx >> 8, jj = idx & 255;
        wl[jj*20 + i] = w[((size_t)b*NSL + i)*NN + jc + jj];
    }
    __syncthreads();
    f4 ax[4], ay[4];
#pragma unroll
    for (int g2 = 0; g2 < 4; g2++){ ax[g2] = f4{0,0,0,0}; ay[g2] = f4{0,0,0,0}; }
    const float2* v2 = (const float2*)(vin + ((size_t)b*NN + jc)*DD);
    const f4* wl4 = (const f4*)wl;
    for (int jj = 0; jj < 256; jj++){
        float2 vv = v2[(size_t)jj*(DD/2) + t];
#pragma unroll
        for (int g2 = 0; g2 < 4; g2++){
            f4 wq = wl4[jj*5 + g2];
            ax[g2].x += wq.x*vv.x; ax[g2].y += wq.y*vv.x; ax[g2].z += wq.z*vv.x; ax[g2].w += wq.w*vv.x;
            ay[g2].x += wq.x*vv.y; ay[g2].y += wq.y*vv.y; ay[g2].z += wq.z*vv.y; ay[g2].w += wq.w*vv.y;
        }
    }
#pragma unroll
    for (int g2 = 0; g2 < 4; g2++){
        const float* px = (const float*)&ax[g2];
        const float* py = (const float*)&ay[g2];
#pragma unroll
        for (int c = 0; c < 4; c++){
            int i = g2*4 + c;
            atomicAdd(&Uw[((size_t)b*NSL + i)*DD + 2*t],     px[c]);
            atomicAdd(&Uw[((size_t)b*NSL + i)*DD + 2*t + 1], py[c]);
        }
    }
}

// ---------------- updates[m,d] = gv[d]*(Uw-M)/S + bv[d] ----------------
__global__ __launch_bounds__(256) void k_upd(const float* __restrict__ Uw, const float* __restrict__ S,
        const float* __restrict__ Mm, const float* __restrict__ gv, const float* __restrict__ bv,
        float* __restrict__ upd){
    int idx = blockIdx.x*256 + threadIdx.x;     // 131072
    int m = idx >> 9, d = idx & 511;
    upd[idx] = gv[d]*(Uw[idx] - Mm[m])/S[m] + bv[d];
}

// ---------------- GRU gate matmuls: gp[m, 0:512]=r_pre, [512:1024]=z_pre, [1024:1536]=nx, [1536:2048]=nh
// grid (32 c-chunks, 8 m-groups), block 256; lane=c, wave -> 8 m's.
__global__ __launch_bounds__(256) void k_gru_mm(const float* __restrict__ x, const float* __restrict__ h,
        const float* __restrict__ Wih, const float* __restrict__ bih,
        const float* __restrict__ Whh, const float* __restrict__ bhh,
        float* __restrict__ gp){
    int lane = threadIdx.x & 63;
    int wv = threadIdx.x >> 6;
    int c = blockIdx.x*64 + lane;               // 0..2047
    int m0 = blockIdx.y*32 + wv*8;
    int type = c >> 9;
    const f4* x4 = (const f4*)x;
    const f4* h4 = (const f4*)h;
    float acc[8] = {0,0,0,0,0,0,0,0};
    float bias;
    if (type <= 1){
        const f4* wi = (const f4*)(Wih + (size_t)c*DD);
        const f4* wh = (const f4*)(Whh + (size_t)c*DD);
        for (int k = 0; k < DD/4; k++){
            f4 a = wi[k], bqv = wh[k];
#pragma unroll
            for (int mm = 0; mm < 8; mm++)
                acc[mm] += dot4f(a, x4[(size_t)(m0+mm)*(DD/4)+k]) + dot4f(bqv, h4[(size_t)(m0+mm)*(DD/4)+k]);
        }
        bias = bih[c] + bhh[c];
    } else if (type == 2){
        const f4* wi = (const f4*)(Wih + (size_t)c*DD);   // rows 1024..1535 = n gate (x part)
        for (int k = 0; k < DD/4; k++){
            f4 a = wi[k];
#pragma unroll
            for (int mm = 0; mm < 8; mm++)
                acc[mm] += dot4f(a, x4[(size_t)(m0+mm)*(DD/4)+k]);
        }
        bias = bih[c];
    } else {
        int cr = c - 512;                                   // rows 1024..1535 of Whh (n gate, h part)
        const f4* wh = (const f4*)(Whh + (size_t)cr*DD);
        for (int k = 0; k < DD/4; k++){
            f4 a = wh[k];
#pragma unroll
            for (int mm = 0; mm < 8; mm++)
                acc[mm] += dot4f(a, h4[(size_t)(m0+mm)*(DD/4)+k]);
        }
        bias = bhh[cr];
    }
#pragma unroll
    for (int mm = 0; mm < 8; mm++)
        gp[(size_t)(m0+mm)*2048 + c] = acc[mm] + bias;
}

// ---------------- GRU elementwise ----------------
__global__ __launch_bounds__(256) void k_gru_elem(const float* __restrict__ gp, const float* __restrict__ h,
                                                  float* __restrict__ slots2){
    int idx = blockIdx.x*256 + threadIdx.x;     // 131072
    int m = idx >> 9, d = idx & 511;
    const float* g = gp + (size_t)m*2048;
    float r = 1.0f/(1.0f + __expf(-g[d]));
    float z = 1.0f/(1.0f + __expf(-g[512+d]));
    float n = tanhf(g[1024+d] + r*g[1536+d]);
    float hh = h[idx];
    slots2[idx] = (1.0f - z)*n + z*hh;
}

// ---------------- FFN1: hid = relu(ffln@W1^T + b1) ----------------
__global__ __launch_bounds__(256) void k_ffn1(const float* __restrict__ a, const float* __restrict__ W1,
                                              const float* __restrict__ b1, float* __restrict__ hid){
    int lane = threadIdx.x & 63;
    int wv = threadIdx.x >> 6;
    int c = blockIdx.x*64 + lane;
    int m0 = blockIdx.y*16 + wv*4;
    const f4* w4 = (const f4*)(W1 + (size_t)c*DD);
    const f4* a4 = (const f4*)a;
    float acc[4] = {0,0,0,0};
    for (int k = 0; k < DD/4; k++){
        f4 w = w4[k];
#pragma unroll
        for (int mm = 0; mm < 4; mm++)
            acc[mm] += dot4f(w, a4[(size_t)(m0+mm)*(DD/4)+k]);
    }
    float bc = b1[c];
#pragma unroll
    for (int mm = 0; mm < 4; mm++)
        hid[(size_t)(m0+mm)*HH + c] = fmaxf(acc[mm] + bc, 0.0f);
}

// ---------------- FFN2: slots = slots2 + hid@W2^T + b2 ----------------
__global__ __launch_bounds__(256) void k_ffn2(const float* __restrict__ hid, const float* __restrict__ W2,
                                              const float* __restrict__ b2, const float* __restrict__ slots2,
                                              float* __restrict__ slots){
    int lane = threadIdx.x & 63;
    int wv = threadIdx.x >> 6;
    int d = blockIdx.x*64 + lane;
    int m0 = blockIdx.y*16 + wv*4;
    const f4* w4 = (const f4*)(W2 + (size_t)d*HH);
    const f4* h4 = (const f4*)hid;
    float acc[4] = {0,0,0,0};
    for (int k = 0; k < HH/4; k++){
        f4 w = w4[k];
#pragma unroll
        for (int mm = 0; mm < 4; mm++)
            acc[mm] += dot4f(w, h4[(size_t)(m0+mm)*(HH/4)+k]);
    }
    float bc = b2[d];
#pragma unroll
    for (int mm = 0; mm < 4; mm++)
        slots[(size_t)(m0+mm)*DD + d] = slots2[(size_t)(m0+mm)*DD + d] + acc[mm] + bc;
}

// ---------------- copy slots to output ----------------
__global__ __launch_bounds__(256) void k_copy(const float* __restrict__ src, float* __restrict__ dst){
    int idx = blockIdx.x*256 + threadIdx.x;   // 32768 float4
    ((f4*)dst)[idx] = ((const f4*)src)[idx];
}

// ---------------- features: pf[b,p,d]=sum_i prm[i,d]*attn[b,i,p]; sf likewise with slots ----------------
// grid (128 p-chunks, 16 b), block 256; thread owns d-pair (2t,2t+1).
__global__ __launch_bounds__(256) void k_features(const float* __restrict__ prompts, const float* __restrict__ slots,
        const float* __restrict__ attn, float* __restrict__ pf, float* __restrict__ sf, float* __restrict__ sf2){
    int b = blockIdx.y;
    int pbase = blockIdx.x*32;
    int t = threadIdx.x;
    __shared__ float al[NSL][33];
    for (int idx = t; idx < NSL*32; idx += 256){
        int i = idx >> 5, p = idx & 31;
        al[i][p] = attn[((size_t)b*NSL + i)*NN + pbase + p];
    }
    float2 pr[NSL], sl[NSL];
    const float2* p2 = (const float2*)prompts;
    const float2* s2 = (const float2*)(slots + (size_t)b*NSL*DD);
#pragma unroll
    for (int i = 0; i < NSL; i++){ pr[i] = p2[i*(DD/2)+t]; sl[i] = s2[i*(DD/2)+t]; }
    __syncthreads();
    for (int p = 0; p < 32; p++){
        float a0 = 0.f, a1 = 0.f, c0 = 0.f, c1 = 0.f;
#pragma unroll
        for (int i = 0; i < NSL; i++){
            float a = al[i][p];
            a0 += a*pr[i].x; a1 += a*pr[i].y;
            c0 += a*sl[i].x; c1 += a*sl[i].y;
        }
        size_t o = ((size_t)b*NN + pbase + p)*DD + 2*t;
        float2 pv; pv.x = a0; pv.y = a1;
        float2 sv; sv.x = c0; sv.y = c1;
        *(float2*)(pf + o) = pv;
        *(float2*)(sf + o) = sv;
        *(float2*)(sf2 + o) = sv;
    }
}

extern "C" void kernel_launch(void* const* d_in, const int* in_sizes, int n_in,
                              void* d_out, int out_size, void* d_ws, size_t ws_size,
                              hipStream_t stream) {
    const float* k_inp   = (const float*)d_in[2];
    const float* v_inp   = (const float*)d_in[3];
    const float* slots_mu= (const float*)d_in[4];
    const float* prompts = (const float*)d_in[5];
    const float* Wq      = (const float*)d_in[6];
    const float* bq      = (const float*)d_in[7];
    const float* W_ih    = (const float*)d_in[8];
    const float* b_ih    = (const float*)d_in[9];
    const float* W_hh    = (const float*)d_in[10];
    const float* b_hh    = (const float*)d_in[11];
    const float* W1      = (const float*)d_in[12];
    const float* b1      = (const float*)d_in[13];
    const float* W2      = (const float*)d_in[14];
    const float* b2      = (const float*)d_in[15];
    const float* gk      = (const float*)d_in[16];
    const float* bk      = (const float*)d_in[17];
    const float* gv      = (const float*)d_in[18];
    const float* bv      = (const float*)d_in[19];
    const float* gs      = (const float*)d_in[20];
    const float* bs      = (const float*)d_in[21];
    const float* gff     = (const float*)d_in[22];
    const float* bff     = (const float*)d_in[23];

    float* ws = (float*)d_ws;
    float* slots   = ws + 0;
    float* slots2  = ws + 131072;
    float* sbuf    = ws + 262144;
    float* qg      = ws + 393216;
    float* updates = ws + 524288;
    float* hid     = ws + 655360;
    float* gate_pre= ws + 786432;
    float* w       = ws + 1310720;
    float* vmu     = ws + 2359296;
    float* vrstd   = ws + 2424832;
    float* C1      = ws + 2490368;
    float* C2      = ws + 2490624;
    float* Uw      = ws + 2490880;
    float* S       = ws + 2621952;
    float* Mm      = ws + 2622208;

    float* out      = (float*)d_out;
    float* attn_out = out + 131072;
    float* pf       = out + 1179648;
    float* sf       = pf + 33554432;
    float* sf2      = sf + 33554432;

    k_bcast<<<128, 256, 0, stream>>>(slots_mu, slots);
    k_vstats<<<256, 256, 0, stream>>>(v_inp, vmu, vrstd);

    for (int it = 0; it < NITERS; it++){
        k_ln_rows<<<256, 64, 0, stream>>>(slots, gs, bs, sbuf);
        hipMemsetAsync(C1, 0, (256 + 256 + 131072)*sizeof(float), stream);
        k_q<<<dim3(8,16), 256, 0, stream>>>(sbuf, Wq, bq, gk, bk, qg, C1, C2);
        k_phase1<<<dim3(16,16), 256, 0, stream>>>(k_inp, qg, C1, C2, vrstd, attn_out, w);
        k_reduceSM<<<dim3(16,16), 256, 0, stream>>>(attn_out, w, vmu, S, Mm);
        k_phase2<<<dim3(16,16), 256, 0, stream>>>(v_inp, w, Uw);
        k_upd<<<512, 256, 0, stream>>>(Uw, S, Mm, gv, bv, updates);
        k_gru_mm<<<dim3(32,8), 256, 0, stream>>>(updates, slots, W_ih, b_ih, W_hh, b_hh, gate_pre);
        k_gru_elem<<<512, 256, 0, stream>>>(gate_pre, slots, slots2);
        k_ln_rows<<<256, 64, 0, stream>>>(slots2, gff, bff, sbuf);
        k_ffn1<<<dim3(8,16), 256, 0, stream>>>(sbuf, W1, b1, hid);
        k_ffn2<<<dim3(8,16), 256, 0, stream>>>(hid, W2, b2, slots2, slots);
    }

    k_copy<<<128, 256, 0, stream>>>(slots, out);
    k_features<<<dim3(128,16), 256, 0, stream>>>(prompts, slots, attn_out, pf, sf, sf2);
}